// Round 26
// baseline (72.811 us; speedup 1.0000x reference)
//
#include <hip/hip_runtime.h>
#include <math.h>

#define BATCH 32
#define NN 1024
#define FF 128
#define HH 128
#define NODES 32   // nodes per block in kernel A
#define PROW 136   // padded P-tile row (bf16) for K=128 chunks

typedef __attribute__((ext_vector_type(8))) short short8v;   // 8 bf16
typedef __attribute__((ext_vector_type(4))) float f32x4;     // MFMA acc

__device__ __forceinline__ unsigned short f2bf(float f) {    // RNE f32->bf16
    unsigned u = __float_as_uint(f);
    u += 0x7fffu + ((u >> 16) & 1u);
    return (unsigned short)(u >> 16);
}

// ---------------- Kernel P: bit-pack adjacency (valid rows only).
// bits[row][j/8] bit (j%8) = adj[row][j] > 0.  96 MB sequential read -> 3 MB.
__global__ __launch_bounds__(256) void gat_pack(
    const float* __restrict__ adj,     // [B,N,N]
    const float* __restrict__ mask,    // [B,N]
    unsigned char* __restrict__ bits)  // [B*N][128]
{
    const int lane = threadIdx.x & 63;
    const int wv = threadIdx.x >> 6;
    const int row = blockIdx.x * 4 + wv;
    if (mask[row] == 0.f) return;            // wave-uniform; bits never read
    const float4* ap = (const float4*)(adj + (size_t)row * NN);
    unsigned int b16 = 0;
#pragma unroll
    for (int q = 0; q < 4; q++) {            // lane covers j = lane*16 .. +15
        const float4 v = ap[lane * 4 + q];
        b16 |= (v.x > 0.f ? 1u : 0u) << (q * 4 + 0);
        b16 |= (v.y > 0.f ? 1u : 0u) << (q * 4 + 1);
        b16 |= (v.z > 0.f ? 1u : 0u) << (q * 4 + 2);
        b16 |= (v.w > 0.f ? 1u : 0u) << (q * 4 + 3);
    }
    ((unsigned short*)(bits + (size_t)row * 128))[lane] = (unsigned short)b16;
}

// ---------------- Kernel A: h = X@W -> g (MFMA-B-fragment-swizzled bf16);
// a_self / a_neigh scalars.  g[(batch,kc,ct,lane=kg*16+li,e)] = h[kc*32+kg*8+e][ct*16+li]
__global__ __launch_bounds__(128) void gat_hidden(
    const float* __restrict__ X,      // [B,N,F]
    const float* __restrict__ W,      // [F,H]
    const float* __restrict__ Wself,  // [H]
    const float* __restrict__ Wneigh, // [H]
    unsigned short* __restrict__ g,   // [B][32 kc][8 ct][64 lane][8] bf16
    float* __restrict__ a_self,       // [B*N]
    float* __restrict__ a_neigh)      // [B*N]
{
    __shared__ float xs[NODES][FF];      // 16 KB
    __shared__ float hs[NODES][HH + 1];  // 16.5 KB
    const int tid = threadIdx.x;
    const long base_node = (long)blockIdx.x * NODES;
    const int batch = (int)(base_node >> 10);
    const int kc = (int)((base_node & 1023) >> 5);   // 32-node chunk index

    const float4* X4 = (const float4*)(X + base_node * FF);
    float4* xs4 = (float4*)&xs[0][0];
#pragma unroll
    for (int k = 0; k < (NODES * FF) / (4 * 128); k++)
        xs4[k * 128 + tid] = X4[k * 128 + tid];
    __syncthreads();

    float acc[NODES];
#pragma unroll
    for (int n = 0; n < NODES; n++) acc[n] = 0.f;
    const int c = tid;
    for (int fq = 0; fq < FF / 4; fq++) {
        const float w0 = W[(4 * fq + 0) * HH + c];
        const float w1 = W[(4 * fq + 1) * HH + c];
        const float w2 = W[(4 * fq + 2) * HH + c];
        const float w3 = W[(4 * fq + 3) * HH + c];
#pragma unroll
        for (int n = 0; n < NODES; n++) {
            const float4 x4 = *(const float4*)&xs[n][4 * fq];
            acc[n] += x4.x * w0 + x4.y * w1 + x4.z * w2 + x4.w * w3;
        }
    }
    {
        const int ct = c >> 4, li = c & 15;
        unsigned short* gb = g + ((((size_t)batch * 32 + kc) * 8 + ct) * 64) * 8;
        union { uint4 q; unsigned short u[8]; } pk;
#pragma unroll
        for (int kg = 0; kg < 4; kg++) {
#pragma unroll
            for (int e = 0; e < 8; e++) pk.u[e] = f2bf(acc[kg * 8 + e]);
            *(uint4*)(gb + (kg * 16 + li) * 8) = pk.q;
        }
    }
#pragma unroll
    for (int n = 0; n < NODES; n++) hs[n][c] = acc[n];
    __syncthreads();

    if (tid < 2 * NODES) {
        const int n = tid & (NODES - 1);
        const float* wvp = (tid < NODES) ? Wself : Wneigh;
        float s = 0.f;
        for (int cc = 0; cc < HH; cc++) s += hs[n][cc] * wvp[cc];
        if (tid < NODES) a_self[base_node + n] = s;
        else             a_neigh[base_node + n] = s;
    }
}

// ---------------- Kernel B: fused P@H (R25 structure), adjacency from BITS.
// 64-row tiles, 8 waves, wave = one ct column x 4 row-tiles, full K,
// K=128 per phase. Stage loads per thread-phase: 16 B bits (L2) + 64 B an
// (L1) instead of 128 B adj (L3). Gate (bits>>c)&1 == (adj>0): p values
// bit-identical to R19..R25. Drain-free barriers; 128-VGPR budget.
__global__ __launch_bounds__(512, 4) void gat_attend(
    const unsigned char* __restrict__ bits, // [B*N][128]
    const float* __restrict__ mask,    // [B,N]
    const unsigned short* __restrict__ g, // swizzled bf16 h
    const float* __restrict__ a_self,  // [B*N]
    const float* __restrict__ a_neigh, // [B*N]
    const float* __restrict__ bvec,    // [H]
    float* __restrict__ out)           // [B,N,H]
{
    const int tid = threadIdx.x;
    const int lane = tid & 63;
    const int wv = tid >> 6;                 // 0..7 = ct column
    // 512 blocks; XCD x owns 4 batches
    const int b = blockIdx.x;
    const int xcd = b & 7;
    const int rest = b >> 3;                 // 0..63
    const int batch = xcd * 4 + (rest >> 4);
    const int tile = rest & 15;              // 0..15 (64-row tiles)
    const int r0 = batch * NN + tile * 64;   // 768 % 64 == 0: tile uniform

    if (mask[r0] == 0.f) {                   // invalid tile: zero-fill out
        float4* o4 = (float4*)(out + (size_t)r0 * HH);
#pragma unroll
        for (int k = 0; k < 4; k++)
            o4[k * 512 + tid] = make_float4(0.f, 0.f, 0.f, 0.f);
        return;
    }

    __shared__ unsigned short P[2][64 * PROW];   // 34816 B
    __shared__ float rtot[64];                   // 256 B

    // staging: thread owns row srow (tid>>3); per phase 16 j's:
    // j = t*128 + kk*32 + c8*4 + 0..3 for kk=0..3
    const int srow = tid >> 3;               // 0..63
    const int c8 = tid & 7;
    const unsigned char* brow = bits + (size_t)(r0 + srow) * 128;
    const float4* anp = (const float4*)(a_neigh + (size_t)batch * NN);
    const float asl = a_self[r0 + srow];
    const unsigned short* gb = g + (size_t)batch * 131072;   // 32*8*64*8
    // gate shift within the phase's uint32 word kk: byte (c8>>1), nibble (c8&1)
    const int bsh = ((c8 >> 1) * 8) + ((c8 & 1) * 4);

    float rs = 0.f;
    unsigned int bw0, bw1, bw2, bw3;         // in-flight bit words (T14)
    float4 pfn[4];                           // in-flight an regs

#define LOADS(t)                                              \
    {                                                         \
        const int o = (t) * 32 + c8;                          \
        const uint4 bq = *(const uint4*)(brow + (t) * 16);    \
        bw0 = bq.x; bw1 = bq.y; bw2 = bq.z; bw3 = bq.w;       \
        pfn[0] = anp[o];       pfn[1] = anp[o + 8];           \
        pfn[2] = anp[o + 16];  pfn[3] = anp[o + 24];          \
    }
    // exp+pack+write one (bitword, anf4) pair -> P[buf] elems kk*32 + c8*4
#define EW(kk, bwk, buf)                                                             \
    {                                                                                \
        const unsigned gate = ((bwk) >> bsh) & 0xfu;                                 \
        const float4 n4 = pfn[kk];                                                   \
        union { unsigned short u[4]; uint2 q; } wq;                                  \
        float x, p;                                                                  \
        x = asl + n4.x; p = (gate & 1u) ? __expf(fmaxf(x, 0.2f * x)) : 0.f;          \
        wq.u[0] = f2bf(p); rs += __uint_as_float((unsigned)wq.u[0] << 16);           \
        x = asl + n4.y; p = (gate & 2u) ? __expf(fmaxf(x, 0.2f * x)) : 0.f;          \
        wq.u[1] = f2bf(p); rs += __uint_as_float((unsigned)wq.u[1] << 16);           \
        x = asl + n4.z; p = (gate & 4u) ? __expf(fmaxf(x, 0.2f * x)) : 0.f;          \
        wq.u[2] = f2bf(p); rs += __uint_as_float((unsigned)wq.u[2] << 16);           \
        x = asl + n4.w; p = (gate & 8u) ? __expf(fmaxf(x, 0.2f * x)) : 0.f;          \
        wq.u[3] = f2bf(p); rs += __uint_as_float((unsigned)wq.u[3] << 16);           \
        *(uint2*)&P[buf][srow * PROW + (kk) * 32 + c8 * 4] = wq.q;                   \
    }
#define EXPWRITE(buf) { EW(0, bw0, buf) EW(1, bw1, buf) EW(2, bw2, buf) EW(3, bw3, buf) }
    // LDS-visibility barrier WITHOUT vmcnt drain: global loads stay in flight.
#define SYNC()                                                  \
    {                                                           \
        asm volatile("s_waitcnt lgkmcnt(0)" ::: "memory");      \
        __builtin_amdgcn_s_barrier();                           \
    }

    f32x4 acc[4];                            // one per 16-row tile
#pragma unroll
    for (int rt = 0; rt < 4; rt++)
#pragma unroll
        for (int i = 0; i < 4; i++) acc[rt][i] = 0.f;

    // prologue: stage phase 0
    LOADS(0)
    EXPWRITE(0)
    SYNC()

    const int li = lane & 15;
    const int kg8 = (lane >> 4) * 8;

    for (int it = 0; it < 8; ++it) {
        const int cur = it & 1;
        // 1. B-loads for this phase (oldest outstanding)
        short8v Bv[4];
#pragma unroll
        for (int kcl = 0; kcl < 4; kcl++)
            Bv[kcl] = *(const short8v*)(gb + ((size_t)((it * 4 + kcl) * 8 + wv) * 64 + lane) * 8);
        // 2. prefetch next phase's bits/an (stays in flight across barrier)
        if (it < 7) LOADS(it + 1)
        // 3. MFMA on P[cur]
#pragma unroll
        for (int kcl = 0; kcl < 4; kcl++) {
#pragma unroll
            for (int rt = 0; rt < 4; rt++) {
                const short8v af = *(const short8v*)&P[cur][(rt * 16 + li) * PROW + kcl * 32 + kg8];
                acc[rt] = __builtin_amdgcn_mfma_f32_16x16x32_bf16(af, Bv[kcl], acc[rt], 0, 0, 0);
            }
        }
        // 4. stage next phase from prefetched regs
        if (it < 7) EXPWRITE(cur ^ 1)
        SYNC()
    }

    // rowsum: 8 threads per row (consecutive lanes) hold partials
    rs += __shfl_xor(rs, 1);
    rs += __shfl_xor(rs, 2);
    rs += __shfl_xor(rs, 4);
    if ((lane & 7) == 0) rtot[srow] = rs;
    __syncthreads();

    // epilogue: wave wv owns out-cols wv*16..+15 for all 64 rows
    const float bv = bvec[wv * 16 + li];
#pragma unroll
    for (int rt = 0; rt < 4; rt++) {
#pragma unroll
        for (int i = 0; i < 4; i++) {
            const int r = rt * 16 + (lane >> 4) * 4 + i;
            const float inv = 1.f / rtot[r];
            out[(size_t)(r0 + r) * HH + wv * 16 + li] = acc[rt][i] * inv + bv;
        }
    }
#undef LOADS
#undef EW
#undef EXPWRITE
#undef SYNC
}

extern "C" void kernel_launch(void* const* d_in, const int* in_sizes, int n_in,
                              void* d_out, int out_size, void* d_ws, size_t ws_size,
                              hipStream_t stream) {
    const float* X      = (const float*)d_in[0];  // M_features [B,N,F]
    const float* adj    = (const float*)d_in[1];  // M_adjacency [B,N,N]
    const float* mask   = (const float*)d_in[2];  // [B,N]
    const float* W      = (const float*)d_in[3];  // [F,H]
    const float* bvec   = (const float*)d_in[4];  // [H]
    const float* Wself  = (const float*)d_in[5];  // [H,1]
    const float* Wneigh = (const float*)d_in[6];  // [H,1]
    float* out = (float*)d_out;

    char* wsb = (char*)d_ws;
    unsigned short* g = (unsigned short*)wsb;                // 8 MB
    float* a_self  = (float*)(wsb + (size_t)BATCH * NN * HH * 2);
    float* a_neigh = a_self + (size_t)BATCH * NN;
    unsigned char* bits = (unsigned char*)(a_neigh + (size_t)BATCH * NN); // 4 MB

    gat_pack<<<(BATCH * NN) / 4, 256, 0, stream>>>(adj, mask, bits);
    gat_hidden<<<(BATCH * NN) / NODES, 128, 0, stream>>>(
        X, W, Wself, Wneigh, g, a_self, a_neigh);
    gat_attend<<<512, 512, 0, stream>>>(
        bits, mask, g, a_self, a_neigh, bvec, out);
}

// Round 28
// 61.374 us; speedup vs baseline: 1.1864x; 1.1864x over previous
//
#include <hip/hip_runtime.h>
#include <math.h>

#define BATCH 32
#define NN 1024
#define FF 128
#define HH 128
#define NODES 32   // nodes per block in kernel A
#define PROW 136   // padded P-tile row (bf16) for K=128 chunks

typedef __attribute__((ext_vector_type(8))) short short8v;   // 8 bf16
typedef __attribute__((ext_vector_type(4))) float f32x4;     // MFMA acc

__device__ __forceinline__ unsigned short f2bf(float f) {    // RNE f32->bf16
    unsigned u = __float_as_uint(f);
    u += 0x7fffu + ((u >> 16) & 1u);
    return (unsigned short)(u >> 16);
}

// ---------------- Kernel A: h = X@W -> g (MFMA-B-fragment-swizzled bf16);
// a_self / a_neigh scalars.  g[(batch,kc,ct,lane=kg*16+li,e)] = h[kc*32+kg*8+e][ct*16+li]
__global__ __launch_bounds__(128) void gat_hidden(
    const float* __restrict__ X,      // [B,N,F]
    const float* __restrict__ W,      // [F,H]
    const float* __restrict__ Wself,  // [H]
    const float* __restrict__ Wneigh, // [H]
    unsigned short* __restrict__ g,   // [B][32 kc][8 ct][64 lane][8] bf16
    float* __restrict__ a_self,       // [B*N]
    float* __restrict__ a_neigh)      // [B*N]
{
    __shared__ float xs[NODES][FF];      // 16 KB
    __shared__ float hs[NODES][HH + 1];  // 16.5 KB
    const int tid = threadIdx.x;
    const long base_node = (long)blockIdx.x * NODES;
    const int batch = (int)(base_node >> 10);
    const int kc = (int)((base_node & 1023) >> 5);   // 32-node chunk index

    const float4* X4 = (const float4*)(X + base_node * FF);
    float4* xs4 = (float4*)&xs[0][0];
#pragma unroll
    for (int k = 0; k < (NODES * FF) / (4 * 128); k++)
        xs4[k * 128 + tid] = X4[k * 128 + tid];
    __syncthreads();

    float acc[NODES];
#pragma unroll
    for (int n = 0; n < NODES; n++) acc[n] = 0.f;
    const int c = tid;
    for (int fq = 0; fq < FF / 4; fq++) {
        const float w0 = W[(4 * fq + 0) * HH + c];
        const float w1 = W[(4 * fq + 1) * HH + c];
        const float w2 = W[(4 * fq + 2) * HH + c];
        const float w3 = W[(4 * fq + 3) * HH + c];
#pragma unroll
        for (int n = 0; n < NODES; n++) {
            const float4 x4 = *(const float4*)&xs[n][4 * fq];
            acc[n] += x4.x * w0 + x4.y * w1 + x4.z * w2 + x4.w * w3;
        }
    }
    {
        const int ct = c >> 4, li = c & 15;
        unsigned short* gb = g + ((((size_t)batch * 32 + kc) * 8 + ct) * 64) * 8;
        union { uint4 q; unsigned short u[8]; } pk;
#pragma unroll
        for (int kg = 0; kg < 4; kg++) {
#pragma unroll
            for (int e = 0; e < 8; e++) pk.u[e] = f2bf(acc[kg * 8 + e]);
            *(uint4*)(gb + (kg * 16 + li) * 8) = pk.q;
        }
    }
#pragma unroll
    for (int n = 0; n < NODES; n++) hs[n][c] = acc[n];
    __syncthreads();

    if (tid < 2 * NODES) {
        const int n = tid & (NODES - 1);
        const float* wvp = (tid < NODES) ? Wself : Wneigh;
        float s = 0.f;
        for (int cc = 0; cc < HH; cc++) s += hs[n][cc] * wvp[cc];
        if (tid < NODES) a_self[base_node + n] = s;
        else             a_neigh[base_node + n] = s;
    }
}

// ---------------- Kernel B: fused P@H (R25 base) + 2-deep B prefetch + setprio.
// 64-row tiles, 8 waves, wave = one ct column x 4 row-tiles, full K,
// K=128 per phase, drain-free barriers, 128-VGPR budget.
// Bv(t+1) issued BEFORE phase t's MFMA cluster (named ping-pong regs) ->
// removes the phase-entry B-load wait from the serial chain. s_setprio(1)
// wraps the MFMA+ds_read cluster (T5: staging/MFMA role diversity exists).
__global__ __launch_bounds__(512, 4) void gat_attend(
    const float* __restrict__ adj,     // [B,N,N]
    const float* __restrict__ mask,    // [B,N]
    const unsigned short* __restrict__ g, // swizzled bf16 h
    const float* __restrict__ a_self,  // [B*N]
    const float* __restrict__ a_neigh, // [B*N]
    const float* __restrict__ bvec,    // [H]
    float* __restrict__ out)           // [B,N,H]
{
    const int tid = threadIdx.x;
    const int lane = tid & 63;
    const int wv = tid >> 6;                 // 0..7 = ct column
    // 512 blocks; XCD x owns 4 batches
    const int b = blockIdx.x;
    const int xcd = b & 7;
    const int rest = b >> 3;                 // 0..63
    const int batch = xcd * 4 + (rest >> 4);
    const int tile = rest & 15;              // 0..15 (64-row tiles)
    const int r0 = batch * NN + tile * 64;   // 768 % 64 == 0: tile uniform

    if (mask[r0] == 0.f) {                   // invalid tile: zero-fill out
        float4* o4 = (float4*)(out + (size_t)r0 * HH);
#pragma unroll
        for (int k = 0; k < 4; k++)
            o4[k * 512 + tid] = make_float4(0.f, 0.f, 0.f, 0.f);
        return;
    }

    __shared__ unsigned short P[2][64 * PROW];   // 34816 B
    __shared__ float rtot[64];                   // 256 B

    // staging: thread owns row srow (tid>>3); per phase 16 j's:
    // j = t*128 + kk*32 + c8*4 + 0..3 for kk=0..3
    const int srow = tid >> 3;               // 0..63
    const int c8 = tid & 7;
    const float4* arow = (const float4*)(adj + (size_t)(r0 + srow) * NN);
    const float4* anp = (const float4*)(a_neigh + (size_t)batch * NN);
    const float asl = a_self[r0 + srow];
    const unsigned short* gb = g + (size_t)batch * 131072;   // 32*8*64*8

    float rs = 0.f;
    float4 pfa[4], pfn[4];                   // in-flight stage registers (T14)

#define LOADS(t)                                              \
    {                                                         \
        const int o = (t) * 32 + c8;                          \
        pfa[0] = arow[o];      pfa[1] = arow[o + 8];          \
        pfa[2] = arow[o + 16]; pfa[3] = arow[o + 24];         \
        pfn[0] = anp[o];       pfn[1] = anp[o + 8];           \
        pfn[2] = anp[o + 16];  pfn[3] = anp[o + 24];          \
    }
    // exp+pack+write one (adjf4, anf4) pair -> P[buf] elems kk*32 + c8*4
#define EW(kk, buf)                                                                  \
    {                                                                                \
        const float4 a4 = pfa[kk]; const float4 n4 = pfn[kk];                        \
        union { unsigned short u[4]; uint2 q; } wq;                                  \
        float x, p;                                                                  \
        x = asl + n4.x; p = (a4.x > 0.f) ? __expf(fmaxf(x, 0.2f * x)) : 0.f;         \
        wq.u[0] = f2bf(p); rs += __uint_as_float((unsigned)wq.u[0] << 16);           \
        x = asl + n4.y; p = (a4.y > 0.f) ? __expf(fmaxf(x, 0.2f * x)) : 0.f;         \
        wq.u[1] = f2bf(p); rs += __uint_as_float((unsigned)wq.u[1] << 16);           \
        x = asl + n4.z; p = (a4.z > 0.f) ? __expf(fmaxf(x, 0.2f * x)) : 0.f;         \
        wq.u[2] = f2bf(p); rs += __uint_as_float((unsigned)wq.u[2] << 16);           \
        x = asl + n4.w; p = (a4.w > 0.f) ? __expf(fmaxf(x, 0.2f * x)) : 0.f;         \
        wq.u[3] = f2bf(p); rs += __uint_as_float((unsigned)wq.u[3] << 16);           \
        *(uint2*)&P[buf][srow * PROW + (kk) * 32 + c8 * 4] = wq.q;                   \
    }
#define EXPWRITE(buf) { EW(0, buf) EW(1, buf) EW(2, buf) EW(3, buf) }
    // LDS-visibility barrier WITHOUT vmcnt drain: global loads stay in flight.
#define SYNC()                                                  \
    {                                                           \
        asm volatile("s_waitcnt lgkmcnt(0)" ::: "memory");      \
        __builtin_amdgcn_s_barrier();                           \
    }
    // explicit 4-register B load (names are BODY params -> substituted first)
#define LOADB4(t, B0, B1, B2, B3)                                                    \
    {                                                                                \
        B0 = *(const short8v*)(gb + ((size_t)(((t) * 4 + 0) * 8 + wv) * 64 + lane) * 8); \
        B1 = *(const short8v*)(gb + ((size_t)(((t) * 4 + 1) * 8 + wv) * 64 + lane) * 8); \
        B2 = *(const short8v*)(gb + ((size_t)(((t) * 4 + 2) * 8 + wv) * 64 + lane) * 8); \
        B3 = *(const short8v*)(gb + ((size_t)(((t) * 4 + 3) * 8 + wv) * 64 + lane) * 8); \
    }

    f32x4 acc[4];                            // one per 16-row tile
#pragma unroll
    for (int rt = 0; rt < 4; rt++)
#pragma unroll
        for (int i = 0; i < 4; i++) acc[rt][i] = 0.f;

    const int li = lane & 15;
    const int kg8 = (lane >> 4) * 8;

    short8v BA0, BA1, BA2, BA3;              // B ping-pong (named, rule #20)
    short8v BB0, BB1, BB2, BB3;

    // prologue: stage phase 0; B(0) flies under the exp work
    LOADS(0)
    LOADB4(0, BA0, BA1, BA2, BA3)
    EXPWRITE(0)
    SYNC()

    // phase body: consume IN B-regs, prefetch OUT B-regs for t+1
#define BODY(t, IN0, IN1, IN2, IN3, OUT0, OUT1, OUT2, OUT3)                          \
    {                                                                                \
        const int cur = (t) & 1;                                                     \
        if ((t) < 7) LOADB4((t) + 1, OUT0, OUT1, OUT2, OUT3)                         \
        if ((t) < 7) LOADS((t) + 1)                                                  \
        __builtin_amdgcn_s_setprio(1);                                               \
        _Pragma("unroll")                                                            \
        for (int rt = 0; rt < 4; rt++) {                                             \
            const short8v af = *(const short8v*)&P[cur][(rt * 16 + li) * PROW + 0 * 32 + kg8]; \
            acc[rt] = __builtin_amdgcn_mfma_f32_16x16x32_bf16(af, IN0, acc[rt], 0, 0, 0);      \
        }                                                                            \
        _Pragma("unroll")                                                            \
        for (int rt = 0; rt < 4; rt++) {                                             \
            const short8v af = *(const short8v*)&P[cur][(rt * 16 + li) * PROW + 1 * 32 + kg8]; \
            acc[rt] = __builtin_amdgcn_mfma_f32_16x16x32_bf16(af, IN1, acc[rt], 0, 0, 0);      \
        }                                                                            \
        _Pragma("unroll")                                                            \
        for (int rt = 0; rt < 4; rt++) {                                             \
            const short8v af = *(const short8v*)&P[cur][(rt * 16 + li) * PROW + 2 * 32 + kg8]; \
            acc[rt] = __builtin_amdgcn_mfma_f32_16x16x32_bf16(af, IN2, acc[rt], 0, 0, 0);      \
        }                                                                            \
        _Pragma("unroll")                                                            \
        for (int rt = 0; rt < 4; rt++) {                                             \
            const short8v af = *(const short8v*)&P[cur][(rt * 16 + li) * PROW + 3 * 32 + kg8]; \
            acc[rt] = __builtin_amdgcn_mfma_f32_16x16x32_bf16(af, IN3, acc[rt], 0, 0, 0);      \
        }                                                                            \
        __builtin_amdgcn_s_setprio(0);                                               \
        if ((t) < 7) EXPWRITE(cur ^ 1)                                               \
        SYNC()                                                                       \
    }

    for (int i2 = 0; i2 < 4; ++i2) {
        const int t0 = 2 * i2;
        BODY(t0,     BA0, BA1, BA2, BA3, BB0, BB1, BB2, BB3)
        BODY(t0 + 1, BB0, BB1, BB2, BB3, BA0, BA1, BA2, BA3)
    }

    // rowsum: 8 threads per row (consecutive lanes) hold partials
    rs += __shfl_xor(rs, 1);
    rs += __shfl_xor(rs, 2);
    rs += __shfl_xor(rs, 4);
    if ((lane & 7) == 0) rtot[srow] = rs;
    __syncthreads();

    // epilogue: wave wv owns out-cols wv*16..+15 for all 64 rows
    const float bv = bvec[wv * 16 + li];
#pragma unroll
    for (int rt = 0; rt < 4; rt++) {
#pragma unroll
        for (int i = 0; i < 4; i++) {
            const int r = rt * 16 + (lane >> 4) * 4 + i;
            const float inv = 1.f / rtot[r];
            out[(size_t)(r0 + r) * HH + wv * 16 + li] = acc[rt][i] * inv + bv;
        }
    }
#undef LOADS
#undef EW
#undef EXPWRITE
#undef SYNC
#undef LOADB4
#undef BODY
}

extern "C" void kernel_launch(void* const* d_in, const int* in_sizes, int n_in,
                              void* d_out, int out_size, void* d_ws, size_t ws_size,
                              hipStream_t stream) {
    const float* X      = (const float*)d_in[0];  // M_features [B,N,F]
    const float* adj    = (const float*)d_in[1];  // M_adjacency [B,N,N]
    const float* mask   = (const float*)d_in[2];  // [B,N]
    const float* W      = (const float*)d_in[3];  // [F,H]
    const float* bvec   = (const float*)d_in[4];  // [H]
    const float* Wself  = (const float*)d_in[5];  // [H,1]
    const float* Wneigh = (const float*)d_in[6];  // [H,1]
    float* out = (float*)d_out;

    char* wsb = (char*)d_ws;
    unsigned short* g = (unsigned short*)wsb;                // 8 MB
    float* a_self  = (float*)(wsb + (size_t)BATCH * NN * HH * 2);
    float* a_neigh = a_self + (size_t)BATCH * NN;

    gat_hidden<<<(BATCH * NN) / NODES, 128, 0, stream>>>(
        X, W, Wself, Wneigh, g, a_self, a_neigh);
    gat_attend<<<512, 512, 0, stream>>>(
        adj, mask, g, a_self, a_neigh, bvec, out);
}

// Round 30
// 58.226 us; speedup vs baseline: 1.2505x; 1.0541x over previous
//
#include <hip/hip_runtime.h>
#include <math.h>

#define BATCH 32
#define NN 1024
#define FF 128
#define HH 128
#define NODES 32   // nodes per block in kernel A
#define PROW 72    // padded P-tile row (bf16): 144B, spreads banks

typedef __attribute__((ext_vector_type(8))) short short8v;   // 8 bf16
typedef __attribute__((ext_vector_type(4))) float f32x4;     // MFMA acc

__device__ __forceinline__ unsigned short f2bf(float f) {    // RNE f32->bf16
    unsigned u = __float_as_uint(f);
    u += 0x7fffu + ((u >> 16) & 1u);
    return (unsigned short)(u >> 16);
}

// ---------------- Kernel A: h = X@W -> g (MFMA-B-fragment-swizzled bf16);
// a_self / a_neigh scalars.  g[(batch,kc,ct,lane=kg*16+li,e)] = h[kc*32+kg*8+e][ct*16+li]
__global__ __launch_bounds__(128) void gat_hidden(
    const float* __restrict__ X,      // [B,N,F]
    const float* __restrict__ W,      // [F,H]
    const float* __restrict__ Wself,  // [H]
    const float* __restrict__ Wneigh, // [H]
    unsigned short* __restrict__ g,   // [B][32 kc][8 ct][64 lane][8] bf16
    float* __restrict__ a_self,       // [B*N]
    float* __restrict__ a_neigh)      // [B*N]
{
    __shared__ float xs[NODES][FF];      // 16 KB
    __shared__ float hs[NODES][HH + 1];  // 16.5 KB
    const int tid = threadIdx.x;
    const long base_node = (long)blockIdx.x * NODES;
    const int batch = (int)(base_node >> 10);
    const int kc = (int)((base_node & 1023) >> 5);   // 32-node chunk index

    const float4* X4 = (const float4*)(X + base_node * FF);
    float4* xs4 = (float4*)&xs[0][0];
#pragma unroll
    for (int k = 0; k < (NODES * FF) / (4 * 128); k++)
        xs4[k * 128 + tid] = X4[k * 128 + tid];
    __syncthreads();

    float acc[NODES];
#pragma unroll
    for (int n = 0; n < NODES; n++) acc[n] = 0.f;
    const int c = tid;
    for (int fq = 0; fq < FF / 4; fq++) {
        const float w0 = W[(4 * fq + 0) * HH + c];
        const float w1 = W[(4 * fq + 1) * HH + c];
        const float w2 = W[(4 * fq + 2) * HH + c];
        const float w3 = W[(4 * fq + 3) * HH + c];
#pragma unroll
        for (int n = 0; n < NODES; n++) {
            const float4 x4 = *(const float4*)&xs[n][4 * fq];
            acc[n] += x4.x * w0 + x4.y * w1 + x4.z * w2 + x4.w * w3;
        }
    }
    {
        const int ct = c >> 4, li = c & 15;
        unsigned short* gb = g + ((((size_t)batch * 32 + kc) * 8 + ct) * 64) * 8;
        union { uint4 q; unsigned short u[8]; } pk;
#pragma unroll
        for (int kg = 0; kg < 4; kg++) {
#pragma unroll
            for (int e = 0; e < 8; e++) pk.u[e] = f2bf(acc[kg * 8 + e]);
            *(uint4*)(gb + (kg * 16 + li) * 8) = pk.q;
        }
    }
#pragma unroll
    for (int n = 0; n < NODES; n++) hs[n][c] = acc[n];
    __syncthreads();

    if (tid < 2 * NODES) {
        const int n = tid & (NODES - 1);
        const float* wvp = (tid < NODES) ? Wself : Wneigh;
        float s = 0.f;
        for (int cc = 0; cc < HH; cc++) s += hs[n][cc] * wvp[cc];
        if (tid < NODES) a_self[base_node + n] = s;
        else             a_neigh[base_node + n] = s;
    }
}

// ---------------- Kernel B: fused P@H (R21 base, __syncthreads everywhere)
// + 2-deep B prefetch (named ping-pong regs) + T5 setprio around MFMA cluster.
// 64-row tiles, 8 waves, wave = one ct column x 4 row-tiles, full K=1024,
// K=64 per iter (16 iters). Unnormalized exp; rowsum of bf16-ROUNDED p.
__global__ __launch_bounds__(512, 4) void gat_attend(
    const float* __restrict__ adj,     // [B,N,N]
    const float* __restrict__ mask,    // [B,N]
    const unsigned short* __restrict__ g, // swizzled bf16 h
    const float* __restrict__ a_self,  // [B*N]
    const float* __restrict__ a_neigh, // [B*N]
    const float* __restrict__ bvec,    // [H]
    float* __restrict__ out)           // [B,N,H]
{
    const int tid = threadIdx.x;
    const int lane = tid & 63;
    const int wv = tid >> 6;                 // 0..7 = ct column
    // 512 blocks; XCD x owns 4 batches
    const int b = blockIdx.x;
    const int xcd = b & 7;
    const int rest = b >> 3;                 // 0..63
    const int batch = xcd * 4 + (rest >> 4);
    const int tile = rest & 15;              // 0..15 (64-row tiles)
    const int r0 = batch * NN + tile * 64;   // 768 % 64 == 0: tile uniform

    if (mask[r0] == 0.f) {                   // invalid tile: zero-fill out
        float4* o4 = (float4*)(out + (size_t)r0 * HH);
#pragma unroll
        for (int k = 0; k < 4; k++)
            o4[k * 512 + tid] = make_float4(0.f, 0.f, 0.f, 0.f);
        return;
    }

    __shared__ unsigned short P[2][64 * PROW];   // 18432 B
    __shared__ float rtot[64];                   // 256 B

    // staging: thread owns row srow (tid>>3), float4-cols c8 and c8+8
    const int srow = tid >> 3;               // 0..63
    const int c8 = tid & 7;
    const float4* arow = (const float4*)(adj + (size_t)(r0 + srow) * NN);
    const float4* anp = (const float4*)(a_neigh + (size_t)batch * NN);
    const float asl = a_self[r0 + srow];
    const unsigned short* gb = g + (size_t)batch * 131072;   // 32*8*64*8

    float rs = 0.f;
    float4 pf_a0, pf_a1, pf_n0, pf_n1;       // in-flight stage registers

#define LOADS(t)                                      \
    {                                                 \
        const int o = (t) * 16 + c8;                  \
        pf_a0 = arow[o];     pf_a1 = arow[o + 8];     \
        pf_n0 = anp[o];      pf_n1 = anp[o + 8];      \
    }
#define EW(a4, n4, elem0, buf)                                                       \
    {                                                                                \
        union { unsigned short u[4]; uint2 q; } wq;                                  \
        float x, p;                                                                  \
        x = asl + n4.x; p = (a4.x > 0.f) ? __expf(fmaxf(x, 0.2f * x)) : 0.f;         \
        wq.u[0] = f2bf(p); rs += __uint_as_float((unsigned)wq.u[0] << 16);           \
        x = asl + n4.y; p = (a4.y > 0.f) ? __expf(fmaxf(x, 0.2f * x)) : 0.f;         \
        wq.u[1] = f2bf(p); rs += __uint_as_float((unsigned)wq.u[1] << 16);           \
        x = asl + n4.z; p = (a4.z > 0.f) ? __expf(fmaxf(x, 0.2f * x)) : 0.f;         \
        wq.u[2] = f2bf(p); rs += __uint_as_float((unsigned)wq.u[2] << 16);           \
        x = asl + n4.w; p = (a4.w > 0.f) ? __expf(fmaxf(x, 0.2f * x)) : 0.f;         \
        wq.u[3] = f2bf(p); rs += __uint_as_float((unsigned)wq.u[3] << 16);           \
        *(uint2*)&P[buf][srow * PROW + (elem0)] = wq.q;                              \
    }
#define EXPWRITE(buf)                        \
    {                                        \
        EW(pf_a0, pf_n0, c8 * 4, buf)        \
        EW(pf_a1, pf_n1, 32 + c8 * 4, buf)   \
    }
    // explicit 2-register B load (names are BODY params -> substituted first)
#define LOADB2(t, B0, B1)                                                            \
    {                                                                                \
        B0 = *(const short8v*)(gb + ((size_t)(((t) * 2 + 0) * 8 + wv) * 64 + lane) * 8); \
        B1 = *(const short8v*)(gb + ((size_t)(((t) * 2 + 1) * 8 + wv) * 64 + lane) * 8); \
    }

    f32x4 acc[4];                            // one per 16-row tile
#pragma unroll
    for (int rt = 0; rt < 4; rt++)
#pragma unroll
        for (int i = 0; i < 4; i++) acc[rt][i] = 0.f;

    const int li = lane & 15;
    const int kg8 = (lane >> 4) * 8;

    short8v BA0, BA1, BB0, BB1;              // B ping-pong (named, rule #20)

    // prologue: stage iter 0; B(0) flies under the exp work
    LOADS(0)
    LOADB2(0, BA0, BA1)
    EXPWRITE(0)
    __syncthreads();

    // iter body: consume IN B-regs, prefetch OUT B-regs for t+1
#define BODY(t, IN0, IN1, OUT0, OUT1)                                                \
    {                                                                                \
        const int cur = (t) & 1;                                                     \
        if ((t) < 15) LOADB2((t) + 1, OUT0, OUT1)                                    \
        if ((t) < 15) LOADS((t) + 1)                                                 \
        __builtin_amdgcn_s_setprio(1);                                               \
        _Pragma("unroll")                                                            \
        for (int rt = 0; rt < 4; rt++) {                                             \
            const short8v af = *(const short8v*)&P[cur][(rt * 16 + li) * PROW + kg8];          \
            acc[rt] = __builtin_amdgcn_mfma_f32_16x16x32_bf16(af, IN0, acc[rt], 0, 0, 0);      \
        }                                                                            \
        _Pragma("unroll")                                                            \
        for (int rt = 0; rt < 4; rt++) {                                             \
            const short8v af = *(const short8v*)&P[cur][(rt * 16 + li) * PROW + 32 + kg8];     \
            acc[rt] = __builtin_amdgcn_mfma_f32_16x16x32_bf16(af, IN1, acc[rt], 0, 0, 0);      \
        }                                                                            \
        __builtin_amdgcn_s_setprio(0);                                               \
        if ((t) < 15) EXPWRITE(cur ^ 1)                                              \
        __syncthreads();                                                             \
    }

    for (int i2 = 0; i2 < 8; ++i2) {
        const int t0 = 2 * i2;
        BODY(t0,     BA0, BA1, BB0, BB1)
        BODY(t0 + 1, BB0, BB1, BA0, BA1)
    }

    // rowsum: 8 threads per row (consecutive lanes) hold partials
    rs += __shfl_xor(rs, 1);
    rs += __shfl_xor(rs, 2);
    rs += __shfl_xor(rs, 4);
    if ((lane & 7) == 0) rtot[srow] = rs;
    __syncthreads();

    // epilogue: wave wv owns out-cols wv*16..+15 for all 64 rows
    const float bv = bvec[wv * 16 + li];
#pragma unroll
    for (int rt = 0; rt < 4; rt++) {
#pragma unroll
        for (int i = 0; i < 4; i++) {
            const int r = rt * 16 + (lane >> 4) * 4 + i;
            const float inv = 1.f / rtot[r];
            out[(size_t)(r0 + r) * HH + wv * 16 + li] = acc[rt][i] * inv + bv;
        }
    }
#undef LOADS
#undef EW
#undef EXPWRITE
#undef LOADB2
#undef BODY
}

extern "C" void kernel_launch(void* const* d_in, const int* in_sizes, int n_in,
                              void* d_out, int out_size, void* d_ws, size_t ws_size,
                              hipStream_t stream) {
    const float* X      = (const float*)d_in[0];  // M_features [B,N,F]
    const float* adj    = (const float*)d_in[1];  // M_adjacency [B,N,N]
    const float* mask   = (const float*)d_in[2];  // [B,N]
    const float* W      = (const float*)d_in[3];  // [F,H]
    const float* bvec   = (const float*)d_in[4];  // [H]
    const float* Wself  = (const float*)d_in[5];  // [H,1]
    const float* Wneigh = (const float*)d_in[6];  // [H,1]
    float* out = (float*)d_out;

    char* wsb = (char*)d_ws;
    unsigned short* g = (unsigned short*)wsb;                // 8 MB
    float* a_self  = (float*)(wsb + (size_t)BATCH * NN * HH * 2);
    float* a_neigh = a_self + (size_t)BATCH * NN;

    gat_hidden<<<(BATCH * NN) / NODES, 128, 0, stream>>>(
        X, W, Wself, Wneigh, g, a_self, a_neigh);
    gat_attend<<<512, 512, 0, stream>>>(
        adj, mask, g, a_self, a_neigh, bvec, out);
}